// Round 6
// baseline (247.197 us; speedup 1.0000x reference)
//
#include <hip/hip_runtime.h>
#include <hip/hip_bf16.h>
#include <math.h>

typedef __attribute__((ext_vector_type(8))) short bf16x8;
typedef __attribute__((ext_vector_type(4))) short bf16x4;
typedef __attribute__((ext_vector_type(4))) float f32x4;

// async global->LDS, 16B per lane. LDS dest = wave-uniform base + lane*16.
static __device__ __forceinline__ void gld16(const void* g, void* l) {
    __builtin_amdgcn_global_load_lds(
        (const __attribute__((address_space(1))) unsigned int*)g,
        (__attribute__((address_space(3))) unsigned int*)l, 16, 0, 0);
}

static __device__ __forceinline__ short f2bf_s(float f) {
    __hip_bfloat16 h = __float2bfloat16(f);
    short s;
    __builtin_memcpy(&s, &h, 2);
    return s;
}

// ---------------------------------------------------------------------------
// Kernel 1: x = LayerNorm(token_embedding + PE)  -> bf16 [4096,1024]
// ---------------------------------------------------------------------------
__global__ __launch_bounds__(256) void peln_kernel(
    const float* __restrict__ emb,
    const float* __restrict__ gamma,
    const float* __restrict__ beta,
    __hip_bfloat16* __restrict__ x)
{
    const int row = blockIdx.x;        // 0..4095
    const int t   = row & 1023;        // position within sequence
    const int tid = threadIdx.x;

    float4 e = ((const float4*)(emb + (size_t)row * 1024))[tid];
    float v[4] = {e.x, e.y, e.z, e.w};
    float s = 0.f, ss = 0.f;
    #pragma unroll
    for (int kk = 0; kk < 4; ++kk) {
        int c = tid * 4 + kk;
        float ang = (float)t * exp2f(-13.287712379549449f * (float)(c >> 1) * (1.0f / 512.0f));
        float pe  = (c & 1) ? cosf(ang) : sinf(ang);
        v[kk] += pe;
        s  += v[kk];
        ss += v[kk] * v[kk];
    }
    #pragma unroll
    for (int off = 1; off < 64; off <<= 1) {
        s  += __shfl_xor(s, off);
        ss += __shfl_xor(ss, off);
    }
    __shared__ float red_s[4], red_ss[4];
    int wave = tid >> 6, lane = tid & 63;
    if (lane == 0) { red_s[wave] = s; red_ss[wave] = ss; }
    __syncthreads();
    float S  = red_s[0] + red_s[1] + red_s[2] + red_s[3];
    float SS = red_ss[0] + red_ss[1] + red_ss[2] + red_ss[3];
    float mu   = S * (1.0f / 1024.0f);
    float var  = SS * (1.0f / 1024.0f) - mu * mu;
    float rstd = rsqrtf(var + 1e-5f);
    #pragma unroll
    for (int kk = 0; kk < 4; ++kk) {
        int c = tid * 4 + kk;
        float y = (v[kk] - mu) * rstd * gamma[c] + beta[c];
        x[(size_t)row * 1024 + c] = __float2bfloat16(y);
    }
}

// ---------------------------------------------------------------------------
// Kernel 2: transpose+cast Wq/Wk/Wv (f32) -> bf16 Wt[3][1024][1024] (N-major)
// ---------------------------------------------------------------------------
__global__ void wt_kernel(const float* __restrict__ Wq,
                          const float* __restrict__ Wk,
                          const float* __restrict__ Wv,
                          __hip_bfloat16* __restrict__ Wt)
{
    __shared__ __hip_bfloat16 tile[32][33];
    int zz = blockIdx.z;
    const float* src = (zz == 0) ? Wq : (zz == 1) ? Wk : Wv;
    __hip_bfloat16* dst = Wt + (size_t)zz * 1024 * 1024;
    int x0 = blockIdx.x * 32, y0 = blockIdx.y * 32;
    int tx = threadIdx.x, ty = threadIdx.y;   // (32,8)
    #pragma unroll
    for (int kk = 0; kk < 4; ++kk)
        tile[ty + 8 * kk][tx] =
            __float2bfloat16(src[(size_t)(y0 + ty + 8 * kk) * 1024 + x0 + tx]);
    __syncthreads();
    #pragma unroll
    for (int kk = 0; kk < 4; ++kk)
        dst[(size_t)(x0 + ty + 8 * kk) * 1024 + y0 + tx] = tile[tx][ty + 8 * kk];
}

// ---------------------------------------------------------------------------
// Kernel 3: fused QKV GEMM, m97 structure + XCD supertiling + XOR-swizzled
// LDS layout: chunk c of row r stored at c^(r&3) -> ds_read_b128 frag reads
// are exactly at the 8-access/bank floor (conflict-free).
// ---------------------------------------------------------------------------
__global__ __launch_bounds__(256) void qkv_gemm(
    const __hip_bfloat16* __restrict__ X,    // [4096,1024] bf16
    const __hip_bfloat16* __restrict__ Wt,   // [3][1024][1024] bf16 N-major
    const float* __restrict__ bq,
    const float* __restrict__ bk,
    const float* __restrict__ bv,
    __hip_bfloat16* __restrict__ qkv)        // [3][4096][1024] bf16
{
    __shared__ __align__(16) __hip_bfloat16 Abuf[128 * 32];  // 8 KB, [row][k]
    __shared__ __align__(16) __hip_bfloat16 Bbuf[128 * 32];  // 8 KB, [n][k]

    const int id   = blockIdx.x;             // 0..767
    const int xcd  = id & 7;
    const int rest = id >> 3;                // 0..95
    const int j    = rest % 3;
    const int mblk = rest / 3;               // 0..31
    const int m0   = mblk * 128;
    const int n0   = (xcd * 3 + j) * 128;    // 0..2944
    const int t    = n0 >> 10;
    const int nn0  = n0 & 1023;
    const __hip_bfloat16* W = Wt + (size_t)t * 1024 * 1024;

    const int tid  = threadIdx.x;
    const int wave = tid >> 6, lane = tid & 63;
    const int wm = wave & 1, wn = wave >> 1;
    const int lm = lane & 15, quad = lane >> 4;

    // staging: row = tid>>2; global col chunk XOR-swizzled so that LDS slot
    // (forced = base + lane*16B) holds logical chunk c at phys c^(row&3)
    const int srow = tid >> 2;
    const int skc  = ((tid & 3) ^ ((tid >> 2) & 3)) * 8;
    const __hip_bfloat16* gA0 = X + (size_t)(m0 + srow) * 1024 + skc;
    const __hip_bfloat16* gA1 = X + (size_t)(m0 + 64 + srow) * 1024 + skc;
    const __hip_bfloat16* gB0 = W + (size_t)(nn0 + srow) * 1024 + skc;
    const __hip_bfloat16* gB1 = W + (size_t)(nn0 + 64 + srow) * 1024 + skc;
    __hip_bfloat16* lA0 = Abuf + wave * 512;
    __hip_bfloat16* lA1 = Abuf + 2048 + wave * 512;
    __hip_bfloat16* lB0 = Bbuf + wave * 512;
    __hip_bfloat16* lB1 = Bbuf + 2048 + wave * 512;

    // fragment read offsets (loop-invariant), phys chunk = quad ^ (row&3)
    const int fcol = (quad ^ (lm & 3)) * 8;

    f32x4 acc[4][4];
    #pragma unroll
    for (int i = 0; i < 4; ++i)
        #pragma unroll
        for (int jj = 0; jj < 4; ++jj)
            acc[i][jj] = (f32x4){0.f, 0.f, 0.f, 0.f};

    for (int k0 = 0; k0 < 1024; k0 += 32) {
        gld16(gA0 + k0, lA0);
        gld16(gA1 + k0, lA1);
        gld16(gB0 + k0, lB0);
        gld16(gB1 + k0, lB1);
        __syncthreads();

        bf16x8 a[4], b[4];
        #pragma unroll
        for (int i = 0; i < 4; ++i)
            a[i] = *(const bf16x8*)(Abuf + (size_t)(wm * 64 + i * 16 + lm) * 32 + fcol);
        #pragma unroll
        for (int jj = 0; jj < 4; ++jj)
            b[jj] = *(const bf16x8*)(Bbuf + (size_t)(wn * 64 + jj * 16 + lm) * 32 + fcol);
        __syncthreads();

        #pragma unroll
        for (int i = 0; i < 4; ++i)
            #pragma unroll
            for (int jj = 0; jj < 4; ++jj)
                acc[i][jj] = __builtin_amdgcn_mfma_f32_16x16x32_bf16(a[i], b[jj], acc[i][jj], 0, 0, 0);
    }

    const float* bias = (t == 0) ? bq : (t == 1) ? bk : bv;
    __hip_bfloat16* out = qkv + (size_t)t * 4096 * 1024;
    #pragma unroll
    for (int jj = 0; jj < 4; ++jj) {
        int col = nn0 + wn * 64 + jj * 16 + lm;
        float bb = bias[col];
        #pragma unroll
        for (int i = 0; i < 4; ++i) {
            #pragma unroll
            for (int r = 0; r < 4; ++r) {
                int row = m0 + wm * 64 + i * 16 + quad * 4 + r;
                out[(size_t)row * 1024 + col] = __float2bfloat16(acc[i][jj][r] + bb);
            }
        }
    }
}

// ---------------------------------------------------------------------------
// Kernel 4: vt[bh][d][n] = v[(b*1024+n)*1024 + h*64 + d]   (V^T per head)
// ---------------------------------------------------------------------------
__global__ void vt_kernel(const __hip_bfloat16* __restrict__ v,
                          __hip_bfloat16* __restrict__ vt)
{
    __shared__ __hip_bfloat16 tile[32][33];
    int bh = blockIdx.z;
    int b = bh >> 4, h = bh & 15;
    int n0 = blockIdx.x * 32, d0 = blockIdx.y * 32;
    int tx = threadIdx.x, ty = threadIdx.y;  // (32,8)
    #pragma unroll
    for (int kk = 0; kk < 4; ++kk)
        tile[ty + 8 * kk][tx] =
            v[(size_t)(b * 1024 + n0 + ty + 8 * kk) * 1024 + h * 64 + d0 + tx];
    __syncthreads();
    #pragma unroll
    for (int kk = 0; kk < 4; ++kk)
        vt[((size_t)bh * 64 + d0 + ty + 8 * kk) * 1024 + n0 + tx] = tile[tx][ty + 8 * kk];
}

// ---------------------------------------------------------------------------
// Kernel 5: flash attention v4 — occupancy-focused. 16 q-rows/wave, 4096
// waves (grid 1024, 4 blocks/CU, 4 waves/SIMD). Transposed MFMA roles
// (S^T = K·Q^T, O^T = V^T·P), max-free softmax, no barriers, no asm drains
// (compiler orders LDS write->read within the wave).
// ---------------------------------------------------------------------------
__global__ __launch_bounds__(256, 4) void attn_kernel(
    const __hip_bfloat16* __restrict__ q,    // [4096,1024]
    const __hip_bfloat16* __restrict__ k,    // [4096,1024]
    const __hip_bfloat16* __restrict__ vt,   // [64][64][1024]
    float* __restrict__ out)                 // [4096,1024] f32
{
    __shared__ short ldsPT[4][2][16][66];    // 16.9 KB
    const int id   = blockIdx.x;             // 0..1023
    const int bh   = (id & 7) * 8 + ((id >> 3) & 7);  // XCD-local K/V
    const int qblk = id >> 6;                // 0..15
    const int b = bh >> 4, h = bh & 15;
    const int wave = threadIdx.x >> 6, lane = threadIdx.x & 63;
    const int lm = lane & 15, quad = lane >> 4;
    const int qbase = qblk * 64 + wave * 16;
    const float CEXP = 0.18033688011112042f;  // (1/8) * log2(e)

    // Q as B-operand frag (n = q = lm, k = d)
    bf16x8 bqf[2];
    #pragma unroll
    for (int ks = 0; ks < 2; ++ks)
        bqf[ks] = *(const bf16x8*)(q + (size_t)(b * 1024 + qbase + lm) * 1024
                                     + h * 64 + ks * 32 + quad * 8);

    const __hip_bfloat16* kbase = k + (size_t)(b * 1024) * 1024 + h * 64;
    const __hip_bfloat16* vbase = vt + (size_t)bh * 64 * 1024;

    f32x4 OT[4];           // [nt = d-tile], C-layout rows = d, cols = q
    float li = 0.f;
    #pragma unroll
    for (int nt = 0; nt < 4; ++nt) OT[nt] = (f32x4){0.f, 0.f, 0.f, 0.f};

    for (int kt = 0; kt < 1024; kt += 64) {
        const int cur = (kt >> 6) & 1;
        // V frags (A-operand of O^T) + K frags (A-operand of S^T)
        bf16x8 av[4][2], ak[4][2];
        #pragma unroll
        for (int nt = 0; nt < 4; ++nt)
            #pragma unroll
            for (int ks = 0; ks < 2; ++ks)
                av[nt][ks] = *(const bf16x8*)(vbase + (size_t)(16 * nt + lm) * 1024
                                                    + kt + ks * 32 + quad * 8);
        #pragma unroll
        for (int jt = 0; jt < 4; ++jt)
            #pragma unroll
            for (int ks = 0; ks < 2; ++ks)
                ak[jt][ks] = *(const bf16x8*)(kbase + (size_t)(kt + 16 * jt + lm) * 1024
                                                    + ks * 32 + quad * 8);
        // S^T = K·Q^T  (rows = keys, cols = q)
        f32x4 ST[4];
        #pragma unroll
        for (int jt = 0; jt < 4; ++jt) {
            ST[jt] = (f32x4){0.f, 0.f, 0.f, 0.f};
            ST[jt] = __builtin_amdgcn_mfma_f32_16x16x32_bf16(ak[jt][0], bqf[0], ST[jt], 0, 0, 0);
            ST[jt] = __builtin_amdgcn_mfma_f32_16x16x32_bf16(ak[jt][1], bqf[1], ST[jt], 0, 0, 0);
        }
        // P = exp2(S*CEXP): 4 consecutive keys per lane -> b64 LDS writes
        #pragma unroll
        for (int jt = 0; jt < 4; ++jt) {
            bf16x4 pk;
            #pragma unroll
            for (int r = 0; r < 4; ++r) {
                float p = __builtin_amdgcn_exp2f(ST[jt][r] * CEXP);
                li += p;
                pk[r] = f2bf_s(p);
            }
            *(bf16x4*)&ldsPT[wave][cur][lm][16 * jt + quad * 4] = pk;
        }
        // P as B-operand (k = key contiguous); compiler inserts lgkm waits
        bf16x8 bp[2];
        #pragma unroll
        for (int ks = 0; ks < 2; ++ks)
            bp[ks] = *(const bf16x8*)&ldsPT[wave][cur][lm][ks * 32 + quad * 8];
        #pragma unroll
        for (int nt = 0; nt < 4; ++nt) {
            OT[nt] = __builtin_amdgcn_mfma_f32_16x16x32_bf16(av[nt][0], bp[0], OT[nt], 0, 0, 0);
            OT[nt] = __builtin_amdgcn_mfma_f32_16x16x32_bf16(av[nt][1], bp[1], OT[nt], 0, 0, 0);
        }
    }

    // li per-lane partial (q = lm): reduce across the 4 quads
    li += __shfl_xor(li, 16);
    li += __shfl_xor(li, 32);
    float inv = 1.0f / li;

    int qrow = qbase + lm;
    #pragma unroll
    for (int nt = 0; nt < 4; ++nt) {
        float4 o4 = {OT[nt][0] * inv, OT[nt][1] * inv,
                     OT[nt][2] * inv, OT[nt][3] * inv};
        *(float4*)(out + (size_t)(b * 1024 + qrow) * 1024 + h * 64 + 16 * nt + quad * 4) = o4;
    }
}

// ---------------------------------------------------------------------------
extern "C" void kernel_launch(void* const* d_in, const int* in_sizes, int n_in,
                              void* d_out, int out_size, void* d_ws, size_t ws_size,
                              hipStream_t stream)
{
    const float* emb   = (const float*)d_in[0];
    const float* gamma = (const float*)d_in[1];
    const float* beta  = (const float*)d_in[2];
    const float* Wq    = (const float*)d_in[3];
    const float* bq    = (const float*)d_in[4];
    const float* Wk    = (const float*)d_in[5];
    const float* bk    = (const float*)d_in[6];
    const float* Wv    = (const float*)d_in[7];
    const float* bv    = (const float*)d_in[8];
    float* out = (float*)d_out;

    __hip_bfloat16* ws  = (__hip_bfloat16*)d_ws;
    __hip_bfloat16* x   = ws;                            //  4M elems bf16
    __hip_bfloat16* Wt  = x   + (size_t)4096 * 1024;     //  3M elems
    __hip_bfloat16* qkv = Wt  + (size_t)3 * 1024 * 1024; // 12M elems
    __hip_bfloat16* vt  = qkv + (size_t)3 * 4096 * 1024; //  4M elems (46MB total)

    peln_kernel<<<4096, 256, 0, stream>>>(emb, gamma, beta, x);
    wt_kernel<<<dim3(32, 32, 3), dim3(32, 8), 0, stream>>>(Wq, Wk, Wv, Wt);
    qkv_gemm<<<768, 256, 0, stream>>>(x, Wt, bq, bk, bv, qkv);
    vt_kernel<<<dim3(32, 2, 64), dim3(32, 8), 0, stream>>>(qkv + (size_t)2 * 4096 * 1024, vt);
    attn_kernel<<<1024, 256, 0, stream>>>(qkv, qkv + (size_t)4096 * 1024, vt, out);
}

// Round 7
// 209.148 us; speedup vs baseline: 1.1819x; 1.1819x over previous
//
#include <hip/hip_runtime.h>
#include <hip/hip_bf16.h>
#include <math.h>

typedef __attribute__((ext_vector_type(8))) short bf16x8;
typedef __attribute__((ext_vector_type(4))) short bf16x4;
typedef __attribute__((ext_vector_type(4))) float f32x4;

// async global->LDS, 16B per lane. LDS dest = wave-uniform base + lane*16.
static __device__ __forceinline__ void gld16(const void* g, void* l) {
    __builtin_amdgcn_global_load_lds(
        (const __attribute__((address_space(1))) unsigned int*)g,
        (__attribute__((address_space(3))) unsigned int*)l, 16, 0, 0);
}

static __device__ __forceinline__ short f2bf_s(float f) {
    __hip_bfloat16 h = __float2bfloat16(f);
    short s;
    __builtin_memcpy(&s, &h, 2);
    return s;
}

// ---------------------------------------------------------------------------
// Kernel 1: x = LayerNorm(token_embedding + PE)  -> bf16 [4096,1024]
// ---------------------------------------------------------------------------
__global__ __launch_bounds__(256) void peln_kernel(
    const float* __restrict__ emb,
    const float* __restrict__ gamma,
    const float* __restrict__ beta,
    __hip_bfloat16* __restrict__ x)
{
    const int row = blockIdx.x;        // 0..4095
    const int t   = row & 1023;        // position within sequence
    const int tid = threadIdx.x;

    float4 e = ((const float4*)(emb + (size_t)row * 1024))[tid];
    float v[4] = {e.x, e.y, e.z, e.w};
    float s = 0.f, ss = 0.f;
    #pragma unroll
    for (int kk = 0; kk < 4; ++kk) {
        int c = tid * 4 + kk;
        float ang = (float)t * exp2f(-13.287712379549449f * (float)(c >> 1) * (1.0f / 512.0f));
        float pe  = (c & 1) ? __cosf(ang) : __sinf(ang);
        v[kk] += pe;
        s  += v[kk];
        ss += v[kk] * v[kk];
    }
    #pragma unroll
    for (int off = 1; off < 64; off <<= 1) {
        s  += __shfl_xor(s, off);
        ss += __shfl_xor(ss, off);
    }
    __shared__ float red_s[4], red_ss[4];
    int wave = tid >> 6, lane = tid & 63;
    if (lane == 0) { red_s[wave] = s; red_ss[wave] = ss; }
    __syncthreads();
    float S  = red_s[0] + red_s[1] + red_s[2] + red_s[3];
    float SS = red_ss[0] + red_ss[1] + red_ss[2] + red_ss[3];
    float mu   = S * (1.0f / 1024.0f);
    float var  = SS * (1.0f / 1024.0f) - mu * mu;
    float rstd = rsqrtf(var + 1e-5f);
    #pragma unroll
    for (int kk = 0; kk < 4; ++kk) {
        int c = tid * 4 + kk;
        float y = (v[kk] - mu) * rstd * gamma[c] + beta[c];
        x[(size_t)row * 1024 + c] = __float2bfloat16(y);
    }
}

// ---------------------------------------------------------------------------
// Kernel 2: transpose+cast Wq/Wk/Wv (f32) -> bf16 Wt[3][1024][1024] (N-major)
// ---------------------------------------------------------------------------
__global__ void wt_kernel(const float* __restrict__ Wq,
                          const float* __restrict__ Wk,
                          const float* __restrict__ Wv,
                          __hip_bfloat16* __restrict__ Wt)
{
    __shared__ __hip_bfloat16 tile[32][33];
    int zz = blockIdx.z;
    const float* src = (zz == 0) ? Wq : (zz == 1) ? Wk : Wv;
    __hip_bfloat16* dst = Wt + (size_t)zz * 1024 * 1024;
    int x0 = blockIdx.x * 32, y0 = blockIdx.y * 32;
    int tx = threadIdx.x, ty = threadIdx.y;   // (32,8)
    #pragma unroll
    for (int kk = 0; kk < 4; ++kk)
        tile[ty + 8 * kk][tx] =
            __float2bfloat16(src[(size_t)(y0 + ty + 8 * kk) * 1024 + x0 + tx]);
    __syncthreads();
    #pragma unroll
    for (int kk = 0; kk < 4; ++kk)
        dst[(size_t)(x0 + ty + 8 * kk) * 1024 + y0 + tx] = tile[tx][ty + 8 * kk];
}

// ---------------------------------------------------------------------------
// Kernel 3: fused QKV GEMM, m97 structure + XCD supertiling + XOR-swizzled LDS
// ---------------------------------------------------------------------------
__global__ __launch_bounds__(256) void qkv_gemm(
    const __hip_bfloat16* __restrict__ X,    // [4096,1024] bf16
    const __hip_bfloat16* __restrict__ Wt,   // [3][1024][1024] bf16 N-major
    const float* __restrict__ bq,
    const float* __restrict__ bk,
    const float* __restrict__ bv,
    __hip_bfloat16* __restrict__ qkv)        // [3][4096][1024] bf16
{
    __shared__ __align__(16) __hip_bfloat16 Abuf[128 * 32];  // 8 KB, [row][k]
    __shared__ __align__(16) __hip_bfloat16 Bbuf[128 * 32];  // 8 KB, [n][k]

    const int id   = blockIdx.x;             // 0..767
    const int xcd  = id & 7;
    const int rest = id >> 3;                // 0..95
    const int j    = rest % 3;
    const int mblk = rest / 3;               // 0..31
    const int m0   = mblk * 128;
    const int n0   = (xcd * 3 + j) * 128;    // 0..2944
    const int t    = n0 >> 10;
    const int nn0  = n0 & 1023;
    const __hip_bfloat16* W = Wt + (size_t)t * 1024 * 1024;

    const int tid  = threadIdx.x;
    const int wave = tid >> 6, lane = tid & 63;
    const int wm = wave & 1, wn = wave >> 1;
    const int lm = lane & 15, quad = lane >> 4;

    const int srow = tid >> 2;
    const int skc  = ((tid & 3) ^ ((tid >> 2) & 3)) * 8;
    const __hip_bfloat16* gA0 = X + (size_t)(m0 + srow) * 1024 + skc;
    const __hip_bfloat16* gA1 = X + (size_t)(m0 + 64 + srow) * 1024 + skc;
    const __hip_bfloat16* gB0 = W + (size_t)(nn0 + srow) * 1024 + skc;
    const __hip_bfloat16* gB1 = W + (size_t)(nn0 + 64 + srow) * 1024 + skc;
    __hip_bfloat16* lA0 = Abuf + wave * 512;
    __hip_bfloat16* lA1 = Abuf + 2048 + wave * 512;
    __hip_bfloat16* lB0 = Bbuf + wave * 512;
    __hip_bfloat16* lB1 = Bbuf + 2048 + wave * 512;

    const int fcol = (quad ^ (lm & 3)) * 8;

    f32x4 acc[4][4];
    #pragma unroll
    for (int i = 0; i < 4; ++i)
        #pragma unroll
        for (int jj = 0; jj < 4; ++jj)
            acc[i][jj] = (f32x4){0.f, 0.f, 0.f, 0.f};

    for (int k0 = 0; k0 < 1024; k0 += 32) {
        gld16(gA0 + k0, lA0);
        gld16(gA1 + k0, lA1);
        gld16(gB0 + k0, lB0);
        gld16(gB1 + k0, lB1);
        __syncthreads();

        bf16x8 a[4], b[4];
        #pragma unroll
        for (int i = 0; i < 4; ++i)
            a[i] = *(const bf16x8*)(Abuf + (size_t)(wm * 64 + i * 16 + lm) * 32 + fcol);
        #pragma unroll
        for (int jj = 0; jj < 4; ++jj)
            b[jj] = *(const bf16x8*)(Bbuf + (size_t)(wn * 64 + jj * 16 + lm) * 32 + fcol);
        __syncthreads();

        #pragma unroll
        for (int i = 0; i < 4; ++i)
            #pragma unroll
            for (int jj = 0; jj < 4; ++jj)
                acc[i][jj] = __builtin_amdgcn_mfma_f32_16x16x32_bf16(a[i], b[jj], acc[i][jj], 0, 0, 0);
    }

    const float* bias = (t == 0) ? bq : (t == 1) ? bk : bv;
    __hip_bfloat16* out = qkv + (size_t)t * 4096 * 1024;
    #pragma unroll
    for (int jj = 0; jj < 4; ++jj) {
        int col = nn0 + wn * 64 + jj * 16 + lm;
        float bb = bias[col];
        #pragma unroll
        for (int i = 0; i < 4; ++i) {
            #pragma unroll
            for (int r = 0; r < 4; ++r) {
                int row = m0 + wm * 64 + i * 16 + quad * 4 + r;
                out[(size_t)row * 1024 + col] = __float2bfloat16(acc[i][jj][r] + bb);
            }
        }
    }
}

// ---------------------------------------------------------------------------
// Kernel 4: vt[bh][d][n] = v[(b*1024+n)*1024 + h*64 + d]   (V^T per head)
// ---------------------------------------------------------------------------
__global__ void vt_kernel(const __hip_bfloat16* __restrict__ v,
                          __hip_bfloat16* __restrict__ vt)
{
    __shared__ __hip_bfloat16 tile[32][33];
    int bh = blockIdx.z;
    int b = bh >> 4, h = bh & 15;
    int n0 = blockIdx.x * 32, d0 = blockIdx.y * 32;
    int tx = threadIdx.x, ty = threadIdx.y;  // (32,8)
    #pragma unroll
    for (int kk = 0; kk < 4; ++kk)
        tile[ty + 8 * kk][tx] =
            v[(size_t)(b * 1024 + n0 + ty + 8 * kk) * 1024 + h * 64 + d0 + tx];
    __syncthreads();
    #pragma unroll
    for (int kk = 0; kk < 4; ++kk)
        vt[((size_t)bh * 64 + d0 + ty + 8 * kk) * 1024 + n0 + tx] = tile[tx][ty + 8 * kk];
}

// ---------------------------------------------------------------------------
// Kernel 5: flash attention v5 — split-K. 32 q-rows/wave (v3's best), each
// wave does HALF the keys (additive partials: max-free softmax). Block =
// (qsub x ksub) waves over 64 q rows; one LDS exchange + one barrier at end.
// Grid 1024 -> 16 waves/CU (2x v3) with UNCHANGED total load traffic.
// ---------------------------------------------------------------------------
__global__ __launch_bounds__(256, 4) void attn_kernel(
    const __hip_bfloat16* __restrict__ q,    // [4096,1024]
    const __hip_bfloat16* __restrict__ k,    // [4096,1024]
    const __hip_bfloat16* __restrict__ vt,   // [64][64][1024]
    float* __restrict__ out)                 // [4096,1024] f32
{
    __shared__ short ldsPT[4][32][72];       // 18,432 B (per-wave P slices)
    __shared__ f32x4 ldsO[2][4][2][64];      // 16,384 B (ksub=1 partial O)
    __shared__ float ldsLi[2][2][16];        // 256 B
    const int id   = blockIdx.x;             // 0..1023
    const int bh   = (id & 7) * 8 + ((id >> 3) & 7);  // XCD-local K/V
    const int qgrp = id >> 6;                // 0..15
    const int b = bh >> 4, h = bh & 15;
    const int wave = threadIdx.x >> 6, lane = threadIdx.x & 63;
    const int qsub = wave & 1, ksub = wave >> 1;
    const int lm = lane & 15, quad = lane >> 4;
    const int qbase = qgrp * 64 + qsub * 32;
    const float CEXP = 0.18033688011112042f; // (1/8) * log2(e)

    // Q as B-operand frags (col n = q = lm, k = d)
    bf16x8 bqf[2][2];
    #pragma unroll
    for (int i = 0; i < 2; ++i)
        #pragma unroll
        for (int ks = 0; ks < 2; ++ks)
            bqf[i][ks] = *(const bf16x8*)(q + (size_t)(b * 1024 + qbase + 16 * i + lm) * 1024
                                            + h * 64 + ks * 32 + quad * 8);

    const __hip_bfloat16* kbase = k + (size_t)(b * 1024 + ksub * 512) * 1024 + h * 64;
    const __hip_bfloat16* vbase = vt + (size_t)bh * 64 * 1024 + ksub * 512;

    f32x4 OT[4][2];        // [nt = d-tile][i = q-tile]; rows = d, cols = q
    float li[2] = {0.f, 0.f};
    #pragma unroll
    for (int nt = 0; nt < 4; ++nt)
        #pragma unroll
        for (int i = 0; i < 2; ++i)
            OT[nt][i] = (f32x4){0.f, 0.f, 0.f, 0.f};

    for (int kt = 0; kt < 512; kt += 64) {
        // ---- S^T = K·Q^T (ks-split ak loads to cap registers) ----
        f32x4 ST[2][4];
        #pragma unroll
        for (int i = 0; i < 2; ++i)
            #pragma unroll
            for (int jt = 0; jt < 4; ++jt)
                ST[i][jt] = (f32x4){0.f, 0.f, 0.f, 0.f};
        #pragma unroll
        for (int ks = 0; ks < 2; ++ks) {
            bf16x8 ak[4];
            #pragma unroll
            for (int jt = 0; jt < 4; ++jt)
                ak[jt] = *(const bf16x8*)(kbase + (size_t)(kt + 16 * jt + lm) * 1024
                                                + ks * 32 + quad * 8);
            #pragma unroll
            for (int i = 0; i < 2; ++i)
                #pragma unroll
                for (int jt = 0; jt < 4; ++jt)
                    ST[i][jt] = __builtin_amdgcn_mfma_f32_16x16x32_bf16(ak[jt], bqf[i][ks], ST[i][jt], 0, 0, 0);
        }
        // prefetch V ks=0 frags (in flight during exp)
        bf16x8 av0[4];
        #pragma unroll
        for (int nt = 0; nt < 4; ++nt)
            av0[nt] = *(const bf16x8*)(vbase + (size_t)(16 * nt + lm) * 1024 + kt + quad * 8);

        // ---- P^T = exp2(S^T*CEXP): 4 consecutive keys/lane -> b64 writes ----
        #pragma unroll
        for (int i = 0; i < 2; ++i)
            #pragma unroll
            for (int jt = 0; jt < 4; ++jt) {
                bf16x4 pk;
                #pragma unroll
                for (int r = 0; r < 4; ++r) {
                    float p = __builtin_amdgcn_exp2f(ST[i][jt][r] * CEXP);
                    li[i] += p;
                    pk[r] = f2bf_s(p);
                }
                *(bf16x4*)&ldsPT[wave][16 * i + lm][16 * jt + quad * 4] = pk;
            }
        asm volatile("s_waitcnt lgkmcnt(0)" ::: "memory");

        // ---- O^T += V^T·P^T (ks-split) ----
        bf16x8 bp[2];
        #pragma unroll
        for (int i = 0; i < 2; ++i)
            bp[i] = *(const bf16x8*)&ldsPT[wave][16 * i + lm][quad * 8];
        #pragma unroll
        for (int nt = 0; nt < 4; ++nt)
            #pragma unroll
            for (int i = 0; i < 2; ++i)
                OT[nt][i] = __builtin_amdgcn_mfma_f32_16x16x32_bf16(av0[nt], bp[i], OT[nt][i], 0, 0, 0);
        bf16x8 av1[4];
        #pragma unroll
        for (int nt = 0; nt < 4; ++nt)
            av1[nt] = *(const bf16x8*)(vbase + (size_t)(16 * nt + lm) * 1024 + kt + 32 + quad * 8);
        #pragma unroll
        for (int i = 0; i < 2; ++i)
            bp[i] = *(const bf16x8*)&ldsPT[wave][16 * i + lm][32 + quad * 8];
        #pragma unroll
        for (int nt = 0; nt < 4; ++nt)
            #pragma unroll
            for (int i = 0; i < 2; ++i)
                OT[nt][i] = __builtin_amdgcn_mfma_f32_16x16x32_bf16(av1[nt], bp[i], OT[nt][i], 0, 0, 0);
        asm volatile("s_waitcnt lgkmcnt(0)" ::: "memory");  // WAR vs next writes
    }

    // reduce li partials across quads (every lane ends with row q = lm's li)
    #pragma unroll
    for (int i = 0; i < 2; ++i) {
        li[i] += __shfl_xor(li[i], 16);
        li[i] += __shfl_xor(li[i], 32);
    }

    // ---- split-K combine: ksub=1 publishes partials, ksub=0 finishes ----
    if (ksub == 1) {
        #pragma unroll
        for (int nt = 0; nt < 4; ++nt)
            #pragma unroll
            for (int i = 0; i < 2; ++i)
                ldsO[qsub][nt][i][quad * 16 + lm] = OT[nt][i];
        if (quad == 0) {
            ldsLi[qsub][0][lm] = li[0];
            ldsLi[qsub][1][lm] = li[1];
        }
    }
    __syncthreads();
    if (ksub == 0) {
        #pragma unroll
        for (int i = 0; i < 2; ++i) {
            float l = li[i] + ldsLi[qsub][i][lm];
            float inv = 1.0f / l;
            int qrow = qbase + 16 * i + lm;
            #pragma unroll
            for (int nt = 0; nt < 4; ++nt) {
                f32x4 o = OT[nt][i] + ldsO[qsub][nt][i][quad * 16 + lm];
                float4 o4 = {o[0] * inv, o[1] * inv, o[2] * inv, o[3] * inv};
                *(float4*)(out + (size_t)(b * 1024 + qrow) * 1024 + h * 64 + 16 * nt + quad * 4) = o4;
            }
        }
    }
}

// ---------------------------------------------------------------------------
extern "C" void kernel_launch(void* const* d_in, const int* in_sizes, int n_in,
                              void* d_out, int out_size, void* d_ws, size_t ws_size,
                              hipStream_t stream)
{
    const float* emb   = (const float*)d_in[0];
    const float* gamma = (const float*)d_in[1];
    const float* beta  = (const float*)d_in[2];
    const float* Wq    = (const float*)d_in[3];
    const float* bq    = (const float*)d_in[4];
    const float* Wk    = (const float*)d_in[5];
    const float* bk    = (const float*)d_in[6];
    const float* Wv    = (const float*)d_in[7];
    const float* bv    = (const float*)d_in[8];
    float* out = (float*)d_out;

    __hip_bfloat16* ws  = (__hip_bfloat16*)d_ws;
    __hip_bfloat16* x   = ws;                            //  4M elems bf16
    __hip_bfloat16* Wt  = x   + (size_t)4096 * 1024;     //  3M elems
    __hip_bfloat16* qkv = Wt  + (size_t)3 * 1024 * 1024; // 12M elems
    __hip_bfloat16* vt  = qkv + (size_t)3 * 4096 * 1024; //  4M elems (46MB total)

    peln_kernel<<<4096, 256, 0, stream>>>(emb, gamma, beta, x);
    wt_kernel<<<dim3(32, 32, 3), dim3(32, 8), 0, stream>>>(Wq, Wk, Wv, Wt);
    qkv_gemm<<<768, 256, 0, stream>>>(x, Wt, bq, bk, bv, qkv);
    vt_kernel<<<dim3(32, 2, 64), dim3(32, 8), 0, stream>>>(qkv + (size_t)2 * 4096 * 1024, vt);
    attn_kernel<<<1024, 256, 0, stream>>>(qkv, qkv + (size_t)4096 * 1024, vt, out);
}

// Round 8
// 209.018 us; speedup vs baseline: 1.1827x; 1.0006x over previous
//
#include <hip/hip_runtime.h>
#include <hip/hip_bf16.h>
#include <math.h>

typedef __attribute__((ext_vector_type(8))) short bf16x8;
typedef __attribute__((ext_vector_type(4))) short bf16x4;
typedef __attribute__((ext_vector_type(4))) float f32x4;

// async global->LDS, 16B per lane. LDS dest = wave-uniform base + lane*16.
static __device__ __forceinline__ void gld16(const void* g, void* l) {
    __builtin_amdgcn_global_load_lds(
        (const __attribute__((address_space(1))) unsigned int*)g,
        (__attribute__((address_space(3))) unsigned int*)l, 16, 0, 0);
}

static __device__ __forceinline__ short f2bf_s(float f) {
    __hip_bfloat16 h = __float2bfloat16(f);
    short s;
    __builtin_memcpy(&s, &h, 2);
    return s;
}

// ---------------------------------------------------------------------------
// Kernel 1: x = LayerNorm(token_embedding + PE)  -> bf16 [4096,1024]
// ---------------------------------------------------------------------------
__global__ __launch_bounds__(256) void peln_kernel(
    const float* __restrict__ emb,
    const float* __restrict__ gamma,
    const float* __restrict__ beta,
    __hip_bfloat16* __restrict__ x)
{
    const int row = blockIdx.x;        // 0..4095
    const int t   = row & 1023;        // position within sequence
    const int tid = threadIdx.x;

    float4 e = ((const float4*)(emb + (size_t)row * 1024))[tid];
    float v[4] = {e.x, e.y, e.z, e.w};
    float s = 0.f, ss = 0.f;
    #pragma unroll
    for (int kk = 0; kk < 4; ++kk) {
        int c = tid * 4 + kk;
        float ang = (float)t * exp2f(-13.287712379549449f * (float)(c >> 1) * (1.0f / 512.0f));
        float pe  = (c & 1) ? __cosf(ang) : __sinf(ang);
        v[kk] += pe;
        s  += v[kk];
        ss += v[kk] * v[kk];
    }
    #pragma unroll
    for (int off = 1; off < 64; off <<= 1) {
        s  += __shfl_xor(s, off);
        ss += __shfl_xor(ss, off);
    }
    __shared__ float red_s[4], red_ss[4];
    int wave = tid >> 6, lane = tid & 63;
    if (lane == 0) { red_s[wave] = s; red_ss[wave] = ss; }
    __syncthreads();
    float S  = red_s[0] + red_s[1] + red_s[2] + red_s[3];
    float SS = red_ss[0] + red_ss[1] + red_ss[2] + red_ss[3];
    float mu   = S * (1.0f / 1024.0f);
    float var  = SS * (1.0f / 1024.0f) - mu * mu;
    float rstd = rsqrtf(var + 1e-5f);
    #pragma unroll
    for (int kk = 0; kk < 4; ++kk) {
        int c = tid * 4 + kk;
        float y = (v[kk] - mu) * rstd * gamma[c] + beta[c];
        x[(size_t)row * 1024 + c] = __float2bfloat16(y);
    }
}

// ---------------------------------------------------------------------------
// Kernel 2: transpose+cast Wq/Wk/Wv (f32) -> bf16 Wt[3][1024][1024] (N-major)
// ---------------------------------------------------------------------------
__global__ void wt_kernel(const float* __restrict__ Wq,
                          const float* __restrict__ Wk,
                          const float* __restrict__ Wv,
                          __hip_bfloat16* __restrict__ Wt)
{
    __shared__ __hip_bfloat16 tile[32][33];
    int zz = blockIdx.z;
    const float* src = (zz == 0) ? Wq : (zz == 1) ? Wk : Wv;
    __hip_bfloat16* dst = Wt + (size_t)zz * 1024 * 1024;
    int x0 = blockIdx.x * 32, y0 = blockIdx.y * 32;
    int tx = threadIdx.x, ty = threadIdx.y;   // (32,8)
    #pragma unroll
    for (int kk = 0; kk < 4; ++kk)
        tile[ty + 8 * kk][tx] =
            __float2bfloat16(src[(size_t)(y0 + ty + 8 * kk) * 1024 + x0 + tx]);
    __syncthreads();
    #pragma unroll
    for (int kk = 0; kk < 4; ++kk)
        dst[(size_t)(x0 + ty + 8 * kk) * 1024 + y0 + tx] = tile[tx][ty + 8 * kk];
}

// ---------------------------------------------------------------------------
// Kernel 3: fused QKV GEMM. m97 structure, BK=64 (16 iters x 32 MFMA),
// XCD supertiling, XOR-swizzled LDS (phys chunk = logical ^ (row&7)):
// ds_read_b128 frag reads exactly 2-way/bank (free).
// ---------------------------------------------------------------------------
__global__ __launch_bounds__(256) void qkv_gemm(
    const __hip_bfloat16* __restrict__ X,    // [4096,1024] bf16
    const __hip_bfloat16* __restrict__ Wt,   // [3][1024][1024] bf16 N-major
    const float* __restrict__ bq,
    const float* __restrict__ bk,
    const float* __restrict__ bv,
    __hip_bfloat16* __restrict__ qkv)        // [3][4096][1024] bf16
{
    __shared__ __align__(16) __hip_bfloat16 Abuf[128 * 64];  // 16 KB [row][k]
    __shared__ __align__(16) __hip_bfloat16 Bbuf[128 * 64];  // 16 KB [n][k]

    const int id   = blockIdx.x;             // 0..767
    const int xcd  = id & 7;
    const int rest = id >> 3;                // 0..95
    const int j    = rest % 3;
    const int mblk = rest / 3;               // 0..31
    const int m0   = mblk * 128;
    const int n0   = (xcd * 3 + j) * 128;    // 0..2944
    const int t    = n0 >> 10;
    const int nn0  = n0 & 1023;
    const __hip_bfloat16* W = Wt + (size_t)t * 1024 * 1024;

    const int tid  = threadIdx.x;
    const int wave = tid >> 6, lane = tid & 63;
    const int wm = wave & 1, wn = wave >> 1;
    const int lm = lane & 15, quad = lane >> 4;

    // staging: per gld16 issue a wave covers 8 rows x 8 chunks(16B).
    // source col chunk = (lane&7) ^ (row&7) so phys slot holds swizzled chunk.
    const int srow = lane >> 3;                        // 0..7
    const int skc  = ((lane & 7) ^ srow) * 8;          // element offset
    const int rbase = wave * 32;                       // rows this wave stages
    const __hip_bfloat16* gA = X + (size_t)(m0 + rbase + srow) * 1024 + skc;
    const __hip_bfloat16* gB = W + (size_t)(nn0 + rbase + srow) * 1024 + skc;
    __hip_bfloat16* lA = Abuf + rbase * 64;
    __hip_bfloat16* lB = Bbuf + rbase * 64;

    f32x4 acc[4][4];
    #pragma unroll
    for (int i = 0; i < 4; ++i)
        #pragma unroll
        for (int jj = 0; jj < 4; ++jj)
            acc[i][jj] = (f32x4){0.f, 0.f, 0.f, 0.f};

    for (int k0 = 0; k0 < 1024; k0 += 64) {
        #pragma unroll
        for (int n = 0; n < 4; ++n) {
            gld16(gA + (size_t)n * 8 * 1024 + k0, lA + n * 8 * 64);
            gld16(gB + (size_t)n * 8 * 1024 + k0, lB + n * 8 * 64);
        }
        __syncthreads();

        bf16x8 a[2][4], b[2][4];
        #pragma unroll
        for (int ks = 0; ks < 2; ++ks) {
            #pragma unroll
            for (int i = 0; i < 4; ++i) {
                int row = wm * 64 + i * 16 + lm;
                a[ks][i] = *(const bf16x8*)(Abuf + (size_t)row * 64
                                            + (((ks * 4 + quad) ^ (lm & 7)) * 8));
            }
            #pragma unroll
            for (int jj = 0; jj < 4; ++jj) {
                int row = wn * 64 + jj * 16 + lm;
                b[ks][jj] = *(const bf16x8*)(Bbuf + (size_t)row * 64
                                             + (((ks * 4 + quad) ^ (lm & 7)) * 8));
            }
        }
        __syncthreads();

        #pragma unroll
        for (int ks = 0; ks < 2; ++ks)
            #pragma unroll
            for (int i = 0; i < 4; ++i)
                #pragma unroll
                for (int jj = 0; jj < 4; ++jj)
                    acc[i][jj] = __builtin_amdgcn_mfma_f32_16x16x32_bf16(a[ks][i], b[ks][jj], acc[i][jj], 0, 0, 0);
    }

    const float* bias = (t == 0) ? bq : (t == 1) ? bk : bv;
    __hip_bfloat16* out = qkv + (size_t)t * 4096 * 1024;
    #pragma unroll
    for (int jj = 0; jj < 4; ++jj) {
        int col = nn0 + wn * 64 + jj * 16 + lm;
        float bb = bias[col];
        #pragma unroll
        for (int i = 0; i < 4; ++i) {
            #pragma unroll
            for (int r = 0; r < 4; ++r) {
                int row = m0 + wm * 64 + i * 16 + quad * 4 + r;
                out[(size_t)row * 1024 + col] = __float2bfloat16(acc[i][jj][r] + bb);
            }
        }
    }
}

// ---------------------------------------------------------------------------
// Kernel 4: vt[bh][d][n] = v[(b*1024+n)*1024 + h*64 + d]   (V^T per head)
// ---------------------------------------------------------------------------
__global__ void vt_kernel(const __hip_bfloat16* __restrict__ v,
                          __hip_bfloat16* __restrict__ vt)
{
    __shared__ __hip_bfloat16 tile[32][33];
    int bh = blockIdx.z;
    int b = bh >> 4, h = bh & 15;
    int n0 = blockIdx.x * 32, d0 = blockIdx.y * 32;
    int tx = threadIdx.x, ty = threadIdx.y;  // (32,8)
    #pragma unroll
    for (int kk = 0; kk < 4; ++kk)
        tile[ty + 8 * kk][tx] =
            v[(size_t)(b * 1024 + n0 + ty + 8 * kk) * 1024 + h * 64 + d0 + tx];
    __syncthreads();
    #pragma unroll
    for (int kk = 0; kk < 4; ++kk)
        vt[((size_t)bh * 64 + d0 + ty + 8 * kk) * 1024 + n0 + tx] = tile[tx][ty + 8 * kk];
}

// ---------------------------------------------------------------------------
// Kernel 5: flash attention v6 — split-K (v5) with spill fix: (256,3) bounds
// (~170 VGPR budget) and NO asm drains (per-wave in-order DS + compiler RAW
// waits). 32 q/wave, half keys/wave, additive partials, 1 barrier total.
// ---------------------------------------------------------------------------
__global__ __launch_bounds__(256, 3) void attn_kernel(
    const __hip_bfloat16* __restrict__ q,    // [4096,1024]
    const __hip_bfloat16* __restrict__ k,    // [4096,1024]
    const __hip_bfloat16* __restrict__ vt,   // [64][64][1024]
    float* __restrict__ out)                 // [4096,1024] f32
{
    __shared__ short ldsPT[4][32][72];       // 18,432 B (per-wave P slices)
    __shared__ f32x4 ldsO[2][4][2][64];      // 16,384 B (ksub=1 partial O)
    __shared__ float ldsLi[2][2][16];        // 256 B
    const int id   = blockIdx.x;             // 0..1023
    const int bh   = (id & 7) * 8 + ((id >> 3) & 7);  // XCD-local K/V
    const int qgrp = id >> 6;                // 0..15
    const int b = bh >> 4, h = bh & 15;
    const int wave = threadIdx.x >> 6, lane = threadIdx.x & 63;
    const int qsub = wave & 1, ksub = wave >> 1;
    const int lm = lane & 15, quad = lane >> 4;
    const int qbase = qgrp * 64 + qsub * 32;
    const float CEXP = 0.18033688011112042f; // (1/8) * log2(e)

    // Q as B-operand frags (col n = q = lm, k = d)
    bf16x8 bqf[2][2];
    #pragma unroll
    for (int i = 0; i < 2; ++i)
        #pragma unroll
        for (int ks = 0; ks < 2; ++ks)
            bqf[i][ks] = *(const bf16x8*)(q + (size_t)(b * 1024 + qbase + 16 * i + lm) * 1024
                                            + h * 64 + ks * 32 + quad * 8);

    const __hip_bfloat16* kbase = k + (size_t)(b * 1024 + ksub * 512) * 1024 + h * 64;
    const __hip_bfloat16* vbase = vt + (size_t)bh * 64 * 1024 + ksub * 512;

    f32x4 OT[4][2];        // [nt = d-tile][i = q-tile]; rows = d, cols = q
    float li[2] = {0.f, 0.f};
    #pragma unroll
    for (int nt = 0; nt < 4; ++nt)
        #pragma unroll
        for (int i = 0; i < 2; ++i)
            OT[nt][i] = (f32x4){0.f, 0.f, 0.f, 0.f};

    for (int kt = 0; kt < 512; kt += 64) {
        // ---- S^T = K·Q^T (ks-split ak loads to cap registers) ----
        f32x4 ST[2][4];
        #pragma unroll
        for (int i = 0; i < 2; ++i)
            #pragma unroll
            for (int jt = 0; jt < 4; ++jt)
                ST[i][jt] = (f32x4){0.f, 0.f, 0.f, 0.f};
        #pragma unroll
        for (int ks = 0; ks < 2; ++ks) {
            bf16x8 ak[4];
            #pragma unroll
            for (int jt = 0; jt < 4; ++jt)
                ak[jt] = *(const bf16x8*)(kbase + (size_t)(kt + 16 * jt + lm) * 1024
                                                + ks * 32 + quad * 8);
            #pragma unroll
            for (int i = 0; i < 2; ++i)
                #pragma unroll
                for (int jt = 0; jt < 4; ++jt)
                    ST[i][jt] = __builtin_amdgcn_mfma_f32_16x16x32_bf16(ak[jt], bqf[i][ks], ST[i][jt], 0, 0, 0);
        }
        // prefetch V ks=0 frags (in flight during exp)
        bf16x8 av0[4];
        #pragma unroll
        for (int nt = 0; nt < 4; ++nt)
            av0[nt] = *(const bf16x8*)(vbase + (size_t)(16 * nt + lm) * 1024 + kt + quad * 8);

        // ---- P^T = exp2(S^T*CEXP): 4 consecutive keys/lane -> b64 writes ----
        #pragma unroll
        for (int i = 0; i < 2; ++i)
            #pragma unroll
            for (int jt = 0; jt < 4; ++jt) {
                bf16x4 pk;
                #pragma unroll
                for (int r = 0; r < 4; ++r) {
                    float p = __builtin_amdgcn_exp2f(ST[i][jt][r] * CEXP);
                    li[i] += p;
                    pk[r] = f2bf_s(p);
                }
                *(bf16x4*)&ldsPT[wave][16 * i + lm][16 * jt + quad * 4] = pk;
            }

        // ---- O^T += V^T·P^T (ks-split); compiler inserts lgkm RAW waits ----
        bf16x8 bp[2];
        #pragma unroll
        for (int i = 0; i < 2; ++i)
            bp[i] = *(const bf16x8*)&ldsPT[wave][16 * i + lm][quad * 8];
        #pragma unroll
        for (int nt = 0; nt < 4; ++nt)
            #pragma unroll
            for (int i = 0; i < 2; ++i)
                OT[nt][i] = __builtin_amdgcn_mfma_f32_16x16x32_bf16(av0[nt], bp[i], OT[nt][i], 0, 0, 0);
        bf16x8 av1[4];
        #pragma unroll
        for (int nt = 0; nt < 4; ++nt)
            av1[nt] = *(const bf16x8*)(vbase + (size_t)(16 * nt + lm) * 1024 + kt + 32 + quad * 8);
        #pragma unroll
        for (int i = 0; i < 2; ++i)
            bp[i] = *(const bf16x8*)&ldsPT[wave][16 * i + lm][32 + quad * 8];
        #pragma unroll
        for (int nt = 0; nt < 4; ++nt)
            #pragma unroll
            for (int i = 0; i < 2; ++i)
                OT[nt][i] = __builtin_amdgcn_mfma_f32_16x16x32_bf16(av1[nt], bp[i], OT[nt][i], 0, 0, 0);
    }

    // reduce li partials across quads (every lane ends with row q = lm's li)
    #pragma unroll
    for (int i = 0; i < 2; ++i) {
        li[i] += __shfl_xor(li[i], 16);
        li[i] += __shfl_xor(li[i], 32);
    }

    // ---- split-K combine: ksub=1 publishes partials, ksub=0 finishes ----
    if (ksub == 1) {
        #pragma unroll
        for (int nt = 0; nt < 4; ++nt)
            #pragma unroll
            for (int i = 0; i < 2; ++i)
                ldsO[qsub][nt][i][quad * 16 + lm] = OT[nt][i];
        if (quad == 0) {
            ldsLi[qsub][0][lm] = li[0];
            ldsLi[qsub][1][lm] = li[1];
        }
    }
    __syncthreads();
    if (ksub == 0) {
        #pragma unroll
        for (int i = 0; i < 2; ++i) {
            float l = li[i] + ldsLi[qsub][i][lm];
            float inv = 1.0f / l;
            int qrow = qbase + 16 * i + lm;
            #pragma unroll
            for (int nt = 0; nt < 4; ++nt) {
                f32x4 o = OT[nt][i] + ldsO[qsub][nt][i][quad * 16 + lm];
                float4 o4 = {o[0] * inv, o[1] * inv, o[2] * inv, o[3] * inv};
                *(float4*)(out + (size_t)(b * 1024 + qrow) * 1024 + h * 64 + 16 * nt + quad * 4) = o4;
            }
        }
    }
}

// ---------------------------------------------------------------------------
extern "C" void kernel_launch(void* const* d_in, const int* in_sizes, int n_in,
                              void* d_out, int out_size, void* d_ws, size_t ws_size,
                              hipStream_t stream)
{
    const float* emb   = (const float*)d_in[0];
    const float* gamma = (const float*)d_in[1];
    const float* beta  = (const float*)d_in[2];
    const float* Wq    = (const float*)d_in[3];
    const float* bq    = (const float*)d_in[4];
    const float* Wk    = (const float*)d_in[5];
    const float* bk    = (const float*)d_in[6];
    const float* Wv    = (const float*)d_in[7];
    const float* bv    = (const float*)d_in[8];
    float* out = (float*)d_out;

    __hip_bfloat16* ws  = (__hip_bfloat16*)d_ws;
    __hip_bfloat16* x   = ws;                            //  4M elems bf16
    __hip_bfloat16* Wt  = x   + (size_t)4096 * 1024;     //  3M elems
    __hip_bfloat16* qkv = Wt  + (size_t)3 * 1024 * 1024; // 12M elems
    __hip_bfloat16* vt  = qkv + (size_t)3 * 4096 * 1024; //  4M elems (46MB total)

    peln_kernel<<<4096, 256, 0, stream>>>(emb, gamma, beta, x);
    wt_kernel<<<dim3(32, 32, 3), dim3(32, 8), 0, stream>>>(Wq, Wk, Wv, Wt);
    qkv_gemm<<<768, 256, 0, stream>>>(x, Wt, bq, bk, bv, qkv);
    vt_kernel<<<dim3(32, 2, 64), dim3(32, 8), 0, stream>>>(qkv + (size_t)2 * 4096 * 1024, vt);
    attn_kernel<<<1024, 256, 0, stream>>>(qkv, qkv + (size_t)4096 * 1024, vt, out);
}

// Round 9
// 165.147 us; speedup vs baseline: 1.4968x; 1.2656x over previous
//
#include <hip/hip_runtime.h>
#include <hip/hip_bf16.h>
#include <math.h>

typedef __attribute__((ext_vector_type(8))) short bf16x8;
typedef __attribute__((ext_vector_type(4))) short bf16x4;
typedef __attribute__((ext_vector_type(4))) float f32x4;

// async global->LDS, 16B per lane. LDS dest = wave-uniform base + lane*16.
static __device__ __forceinline__ void gld16(const void* g, void* l) {
    __builtin_amdgcn_global_load_lds(
        (const __attribute__((address_space(1))) unsigned int*)g,
        (__attribute__((address_space(3))) unsigned int*)l, 16, 0, 0);
}

static __device__ __forceinline__ short f2bf_s(float f) {
    __hip_bfloat16 h = __float2bfloat16(f);
    short s;
    __builtin_memcpy(&s, &h, 2);
    return s;
}

// ---------------------------------------------------------------------------
// Kernel 1: x = LayerNorm(token_embedding + PE)  -> bf16 [4096,1024]
// ---------------------------------------------------------------------------
__global__ __launch_bounds__(256) void peln_kernel(
    const float* __restrict__ emb,
    const float* __restrict__ gamma,
    const float* __restrict__ beta,
    __hip_bfloat16* __restrict__ x)
{
    const int row = blockIdx.x;        // 0..4095
    const int t   = row & 1023;        // position within sequence
    const int tid = threadIdx.x;

    float4 e = ((const float4*)(emb + (size_t)row * 1024))[tid];
    float v[4] = {e.x, e.y, e.z, e.w};
    float s = 0.f, ss = 0.f;
    #pragma unroll
    for (int kk = 0; kk < 4; ++kk) {
        int c = tid * 4 + kk;
        float ang = (float)t * exp2f(-13.287712379549449f * (float)(c >> 1) * (1.0f / 512.0f));
        float pe  = (c & 1) ? __cosf(ang) : __sinf(ang);
        v[kk] += pe;
        s  += v[kk];
        ss += v[kk] * v[kk];
    }
    #pragma unroll
    for (int off = 1; off < 64; off <<= 1) {
        s  += __shfl_xor(s, off);
        ss += __shfl_xor(ss, off);
    }
    __shared__ float red_s[4], red_ss[4];
    int wave = tid >> 6, lane = tid & 63;
    if (lane == 0) { red_s[wave] = s; red_ss[wave] = ss; }
    __syncthreads();
    float S  = red_s[0] + red_s[1] + red_s[2] + red_s[3];
    float SS = red_ss[0] + red_ss[1] + red_ss[2] + red_ss[3];
    float mu   = S * (1.0f / 1024.0f);
    float var  = SS * (1.0f / 1024.0f) - mu * mu;
    float rstd = rsqrtf(var + 1e-5f);
    #pragma unroll
    for (int kk = 0; kk < 4; ++kk) {
        int c = tid * 4 + kk;
        float y = (v[kk] - mu) * rstd * gamma[c] + beta[c];
        x[(size_t)row * 1024 + c] = __float2bfloat16(y);
    }
}

// ---------------------------------------------------------------------------
// Kernel 2: transpose+cast Wq/Wk/Wv (f32) -> bf16 Wt[3][1024][1024] (N-major)
// ---------------------------------------------------------------------------
__global__ void wt_kernel(const float* __restrict__ Wq,
                          const float* __restrict__ Wk,
                          const float* __restrict__ Wv,
                          __hip_bfloat16* __restrict__ Wt)
{
    __shared__ __hip_bfloat16 tile[32][33];
    int zz = blockIdx.z;
    const float* src = (zz == 0) ? Wq : (zz == 1) ? Wk : Wv;
    __hip_bfloat16* dst = Wt + (size_t)zz * 1024 * 1024;
    int x0 = blockIdx.x * 32, y0 = blockIdx.y * 32;
    int tx = threadIdx.x, ty = threadIdx.y;   // (32,8)
    #pragma unroll
    for (int kk = 0; kk < 4; ++kk)
        tile[ty + 8 * kk][tx] =
            __float2bfloat16(src[(size_t)(y0 + ty + 8 * kk) * 1024 + x0 + tx]);
    __syncthreads();
    #pragma unroll
    for (int kk = 0; kk < 4; ++kk)
        dst[(size_t)(x0 + ty + 8 * kk) * 1024 + y0 + tx] = tile[tx][ty + 8 * kk];
}

// ---------------------------------------------------------------------------
// Kernel 3: fused QKV GEMM. m97 loop (BK=64, XOR-swizzled LDS) + coalesced
// LDS-bounce epilogue (8x16B stores/thread instead of 64 scattered 2B).
// ---------------------------------------------------------------------------
__global__ __launch_bounds__(256) void qkv_gemm(
    const __hip_bfloat16* __restrict__ X,    // [4096,1024] bf16
    const __hip_bfloat16* __restrict__ Wt,   // [3][1024][1024] bf16 N-major
    const float* __restrict__ bq,
    const float* __restrict__ bk,
    const float* __restrict__ bv,
    __hip_bfloat16* __restrict__ qkv)        // [3][4096][1024] bf16
{
    union SMem {
        struct { __hip_bfloat16 A[128 * 64]; __hip_bfloat16 B[128 * 64]; } s;
        __hip_bfloat16 C[128 * 132];         // epilogue bounce (pad 132)
    };
    __shared__ __align__(16) SMem sm;

    const int id   = blockIdx.x;             // 0..767
    const int xcd  = id & 7;
    const int rest = id >> 3;                // 0..95
    const int j    = rest % 3;
    const int mblk = rest / 3;               // 0..31
    const int m0   = mblk * 128;
    const int n0   = (xcd * 3 + j) * 128;    // 0..2944
    const int t    = n0 >> 10;
    const int nn0  = n0 & 1023;
    const __hip_bfloat16* W = Wt + (size_t)t * 1024 * 1024;

    const int tid  = threadIdx.x;
    const int wave = tid >> 6, lane = tid & 63;
    const int wm = wave & 1, wn = wave >> 1;
    const int lm = lane & 15, quad = lane >> 4;

    const int srow = lane >> 3;                        // 0..7
    const int skc  = ((lane & 7) ^ srow) * 8;          // element offset
    const int rbase = wave * 32;                       // rows this wave stages
    const __hip_bfloat16* gA = X + (size_t)(m0 + rbase + srow) * 1024 + skc;
    const __hip_bfloat16* gB = W + (size_t)(nn0 + rbase + srow) * 1024 + skc;
    __hip_bfloat16* lA = sm.s.A + rbase * 64;
    __hip_bfloat16* lB = sm.s.B + rbase * 64;

    f32x4 acc[4][4];
    #pragma unroll
    for (int i = 0; i < 4; ++i)
        #pragma unroll
        for (int jj = 0; jj < 4; ++jj)
            acc[i][jj] = (f32x4){0.f, 0.f, 0.f, 0.f};

    for (int k0 = 0; k0 < 1024; k0 += 64) {
        #pragma unroll
        for (int n = 0; n < 4; ++n) {
            gld16(gA + (size_t)n * 8 * 1024 + k0, lA + n * 8 * 64);
            gld16(gB + (size_t)n * 8 * 1024 + k0, lB + n * 8 * 64);
        }
        __syncthreads();

        bf16x8 a[2][4], b[2][4];
        #pragma unroll
        for (int ks = 0; ks < 2; ++ks) {
            #pragma unroll
            for (int i = 0; i < 4; ++i) {
                int row = wm * 64 + i * 16 + lm;
                a[ks][i] = *(const bf16x8*)(sm.s.A + (size_t)row * 64
                                            + (((ks * 4 + quad) ^ (lm & 7)) * 8));
            }
            #pragma unroll
            for (int jj = 0; jj < 4; ++jj) {
                int row = wn * 64 + jj * 16 + lm;
                b[ks][jj] = *(const bf16x8*)(sm.s.B + (size_t)row * 64
                                             + (((ks * 4 + quad) ^ (lm & 7)) * 8));
            }
        }
        __syncthreads();

        #pragma unroll
        for (int ks = 0; ks < 2; ++ks)
            #pragma unroll
            for (int i = 0; i < 4; ++i)
                #pragma unroll
                for (int jj = 0; jj < 4; ++jj)
                    acc[i][jj] = __builtin_amdgcn_mfma_f32_16x16x32_bf16(a[ks][i], b[ks][jj], acc[i][jj], 0, 0, 0);
    }

    // ---- coalesced epilogue: acc -> LDS (bf16, +bias) -> 16B global stores
    const float* bias = (t == 0) ? bq : (t == 1) ? bk : bv;
    #pragma unroll
    for (int jj = 0; jj < 4; ++jj) {
        int col = wn * 64 + jj * 16 + lm;
        float bb = bias[nn0 + col];
        #pragma unroll
        for (int i = 0; i < 4; ++i)
            #pragma unroll
            for (int r = 0; r < 4; ++r) {
                int row = wm * 64 + i * 16 + quad * 4 + r;
                sm.C[(size_t)row * 132 + col] = __float2bfloat16(acc[i][jj][r] + bb);
            }
    }
    __syncthreads();
    __hip_bfloat16* out = qkv + (size_t)t * 4096 * 1024;
    #pragma unroll
    for (int c = 0; c < 8; ++c) {
        int g = tid + 256 * c;               // 0..2047 chunks of 16B
        int row = g >> 4;
        int colc = (g & 15) * 8;
        bf16x8 vch = *(const bf16x8*)&sm.C[(size_t)row * 132 + colc];
        *(bf16x8*)(out + (size_t)(m0 + row) * 1024 + nn0 + colc) = vch;
    }
}

// ---------------------------------------------------------------------------
// Kernel 4: vt[bh][d][n] = v[(b*1024+n)*1024 + h*64 + d]   (V^T per head)
// ---------------------------------------------------------------------------
__global__ void vt_kernel(const __hip_bfloat16* __restrict__ v,
                          __hip_bfloat16* __restrict__ vt)
{
    __shared__ __hip_bfloat16 tile[32][33];
    int bh = blockIdx.z;
    int b = bh >> 4, h = bh & 15;
    int n0 = blockIdx.x * 32, d0 = blockIdx.y * 32;
    int tx = threadIdx.x, ty = threadIdx.y;  // (32,8)
    #pragma unroll
    for (int kk = 0; kk < 4; ++kk)
        tile[ty + 8 * kk][tx] =
            v[(size_t)(b * 1024 + n0 + ty + 8 * kk) * 1024 + h * 64 + d0 + tx];
    __syncthreads();
    #pragma unroll
    for (int kk = 0; kk < 4; ++kk)
        vt[((size_t)bh * 64 + d0 + ty + 8 * kk) * 1024 + n0 + tx] = tile[tx][ty + 8 * kk];
}

// ---------------------------------------------------------------------------
// Kernel 5: flash attention v7 — LDS-staged K/V (coalesced global_load_lds,
// XOR-swizzled; kills the scattered-fragment TA bottleneck). 128 q/block,
// 32 q/wave, full 1024 keys, max-free softmax, P^T via wave-private LDS.
// ---------------------------------------------------------------------------
__global__ __launch_bounds__(256, 2) void attn_kernel(
    const __hip_bfloat16* __restrict__ q,    // [4096,1024]
    const __hip_bfloat16* __restrict__ k,    // [4096,1024]
    const __hip_bfloat16* __restrict__ vt,   // [64][64][1024]
    float* __restrict__ out)                 // [4096,1024] f32
{
    __shared__ __align__(16) __hip_bfloat16 Kbuf[64 * 64];   // 8 KB [key][d]
    __shared__ __align__(16) __hip_bfloat16 Vbuf[64 * 64];   // 8 KB [d][key]
    __shared__ short ldsPT[4][32][72];                        // 18 KB
    const int id   = blockIdx.x;             // 0..511
    const int bh   = (id & 7) * 8 + ((id >> 3) & 7);  // XCD-local K/V
    const int qblk = id >> 6;                // 0..7
    const int b = bh >> 4, h = bh & 15;
    const int wave = threadIdx.x >> 6, lane = threadIdx.x & 63;
    const int lm = lane & 15, quad = lane >> 4;
    const int qbase = qblk * 128 + wave * 32;
    const float CEXP = 0.18033688011112042f; // (1/8) * log2(e)

    // Q as B-operand frags (col n = q = lm, k = d) — loaded once
    bf16x8 bqf[2][2];
    #pragma unroll
    for (int i = 0; i < 2; ++i)
        #pragma unroll
        for (int ks = 0; ks < 2; ++ks)
            bqf[i][ks] = *(const bf16x8*)(q + (size_t)(b * 1024 + qbase + 16 * i + lm) * 1024
                                            + h * 64 + ks * 32 + quad * 8);

    const __hip_bfloat16* kg = k + (size_t)(b * 1024) * 1024 + h * 64;   // [key][d]
    const __hip_bfloat16* vg = vt + (size_t)bh * 64 * 1024;              // [d][key]
    const int srow = lane >> 3;                  // 0..7
    const int skc  = ((lane & 7) ^ srow) * 8;    // swizzled source chunk

    f32x4 OT[4][2];        // [nt = d-tile][i = q-tile]; rows = d, cols = q
    float li[2] = {0.f, 0.f};
    #pragma unroll
    for (int nt = 0; nt < 4; ++nt)
        #pragma unroll
        for (int i = 0; i < 2; ++i)
            OT[nt][i] = (f32x4){0.f, 0.f, 0.f, 0.f};

    for (int kt = 0; kt < 1024; kt += 64) {
        // ---- stage K-tile [64 keys][64 d] and V-tile [64 d][64 keys] ----
        #pragma unroll
        for (int n = 0; n < 2; ++n) {
            int r0 = n * 32 + wave * 8;
            gld16(kg + (size_t)(kt + r0 + srow) * 1024 + skc, Kbuf + r0 * 64);
            gld16(vg + (size_t)(r0 + srow) * 1024 + kt + skc, Vbuf + r0 * 64);
        }
        __syncthreads();

        bf16x8 ak[4][2], av[4][2];
        #pragma unroll
        for (int jt = 0; jt < 4; ++jt)
            #pragma unroll
            for (int ks = 0; ks < 2; ++ks)
                ak[jt][ks] = *(const bf16x8*)(Kbuf + (size_t)(16 * jt + lm) * 64
                                              + (((ks * 4 + quad) ^ (lm & 7)) * 8));
        #pragma unroll
        for (int nt = 0; nt < 4; ++nt)
            #pragma unroll
            for (int ks = 0; ks < 2; ++ks)
                av[nt][ks] = *(const bf16x8*)(Vbuf + (size_t)(16 * nt + lm) * 64
                                              + (((ks * 4 + quad) ^ (lm & 7)) * 8));
        __syncthreads();

        // ---- S^T = K·Q^T ----
        f32x4 ST[2][4];
        #pragma unroll
        for (int i = 0; i < 2; ++i)
            #pragma unroll
            for (int jt = 0; jt < 4; ++jt)
                ST[i][jt] = (f32x4){0.f, 0.f, 0.f, 0.f};
        #pragma unroll
        for (int ks = 0; ks < 2; ++ks)
            #pragma unroll
            for (int i = 0; i < 2; ++i)
                #pragma unroll
                for (int jt = 0; jt < 4; ++jt)
                    ST[i][jt] = __builtin_amdgcn_mfma_f32_16x16x32_bf16(ak[jt][ks], bqf[i][ks], ST[i][jt], 0, 0, 0);

        // ---- P^T = exp2(S^T*CEXP): 4 consecutive keys/lane -> b64 writes ----
        #pragma unroll
        for (int i = 0; i < 2; ++i)
            #pragma unroll
            for (int jt = 0; jt < 4; ++jt) {
                bf16x4 pk;
                #pragma unroll
                for (int r = 0; r < 4; ++r) {
                    float p = __builtin_amdgcn_exp2f(ST[i][jt][r] * CEXP);
                    li[i] += p;
                    pk[r] = f2bf_s(p);
                }
                *(bf16x4*)&ldsPT[wave][16 * i + lm][16 * jt + quad * 4] = pk;
            }

        // ---- O^T += V^T·P^T (compiler inserts lgkm RAW waits) ----
        bf16x8 bp[2][2];
        #pragma unroll
        for (int i = 0; i < 2; ++i)
            #pragma unroll
            for (int ks = 0; ks < 2; ++ks)
                bp[i][ks] = *(const bf16x8*)&ldsPT[wave][16 * i + lm][ks * 32 + quad * 8];
        #pragma unroll
        for (int ks = 0; ks < 2; ++ks)
            #pragma unroll
            for (int nt = 0; nt < 4; ++nt)
                #pragma unroll
                for (int i = 0; i < 2; ++i)
                    OT[nt][i] = __builtin_amdgcn_mfma_f32_16x16x32_bf16(av[nt][ks], bp[i][ks], OT[nt][i], 0, 0, 0);
    }

    // li per-lane partial (q = lm): reduce across the 4 quads
    #pragma unroll
    for (int i = 0; i < 2; ++i) {
        li[i] += __shfl_xor(li[i], 16);
        li[i] += __shfl_xor(li[i], 32);
    }

    #pragma unroll
    for (int i = 0; i < 2; ++i) {
        float inv = 1.0f / li[i];
        int qrow = qbase + 16 * i + lm;
        #pragma unroll
        for (int nt = 0; nt < 4; ++nt) {
            float4 o4 = {OT[nt][i][0] * inv, OT[nt][i][1] * inv,
                         OT[nt][i][2] * inv, OT[nt][i][3] * inv};
            *(float4*)(out + (size_t)(b * 1024 + qrow) * 1024 + h * 64 + 16 * nt + quad * 4) = o4;
        }
    }
}

// ---------------------------------------------------------------------------
extern "C" void kernel_launch(void* const* d_in, const int* in_sizes, int n_in,
                              void* d_out, int out_size, void* d_ws, size_t ws_size,
                              hipStream_t stream)
{
    const float* emb   = (const float*)d_in[0];
    const float* gamma = (const float*)d_in[1];
    const float* beta  = (const float*)d_in[2];
    const float* Wq    = (const float*)d_in[3];
    const float* bq    = (const float*)d_in[4];
    const float* Wk    = (const float*)d_in[5];
    const float* bk    = (const float*)d_in[6];
    const float* Wv    = (const float*)d_in[7];
    const float* bv    = (const float*)d_in[8];
    float* out = (float*)d_out;

    __hip_bfloat16* ws  = (__hip_bfloat16*)d_ws;
    __hip_bfloat16* x   = ws;                            //  4M elems bf16
    __hip_bfloat16* Wt  = x   + (size_t)4096 * 1024;     //  3M elems
    __hip_bfloat16* qkv = Wt  + (size_t)3 * 1024 * 1024; // 12M elems
    __hip_bfloat16* vt  = qkv + (size_t)3 * 4096 * 1024; //  4M elems (46MB total)

    peln_kernel<<<4096, 256, 0, stream>>>(emb, gamma, beta, x);
    wt_kernel<<<dim3(32, 32, 3), dim3(32, 8), 0, stream>>>(Wq, Wk, Wv, Wt);
    qkv_gemm<<<768, 256, 0, stream>>>(x, Wt, bq, bk, bv, qkv);
    vt_kernel<<<dim3(32, 2, 64), dim3(32, 8), 0, stream>>>(qkv + (size_t)2 * 4096 * 1024, vt);
    attn_kernel<<<512, 256, 0, stream>>>(qkv, qkv + (size_t)4096 * 1024, vt, out);
}

// Round 10
// 156.048 us; speedup vs baseline: 1.5841x; 1.0583x over previous
//
#include <hip/hip_runtime.h>
#include <hip/hip_bf16.h>
#include <math.h>

typedef __attribute__((ext_vector_type(8))) short bf16x8;
typedef __attribute__((ext_vector_type(4))) short bf16x4;
typedef __attribute__((ext_vector_type(4))) float f32x4;

// async global->LDS, 16B per lane. LDS dest = wave-uniform base + lane*16.
static __device__ __forceinline__ void gld16(const void* g, void* l) {
    __builtin_amdgcn_global_load_lds(
        (const __attribute__((address_space(1))) unsigned int*)g,
        (__attribute__((address_space(3))) unsigned int*)l, 16, 0, 0);
}

static __device__ __forceinline__ short f2bf_s(float f) {
    __hip_bfloat16 h = __float2bfloat16(f);
    short s;
    __builtin_memcpy(&s, &h, 2);
    return s;
}

// ---------------------------------------------------------------------------
// Kernel 1: merged PE+LayerNorm (blocks 0..4095) and W transpose+cast
// (blocks 4096..7167). Independent work, block-uniform branch.
// ---------------------------------------------------------------------------
__global__ __launch_bounds__(256) void peln_wt_kernel(
    const float* __restrict__ emb,
    const float* __restrict__ gamma,
    const float* __restrict__ beta,
    const float* __restrict__ Wq,
    const float* __restrict__ Wk,
    const float* __restrict__ Wv,
    __hip_bfloat16* __restrict__ x,
    __hip_bfloat16* __restrict__ Wt)
{
    const int tid = threadIdx.x;
    if (blockIdx.x < 4096) {
        // ---- PE + LayerNorm ----
        const int row = blockIdx.x;
        const int t   = row & 1023;
        float4 e = ((const float4*)(emb + (size_t)row * 1024))[tid];
        float v[4] = {e.x, e.y, e.z, e.w};
        float s = 0.f, ss = 0.f;
        #pragma unroll
        for (int kk = 0; kk < 4; ++kk) {
            int c = tid * 4 + kk;
            float ang = (float)t * exp2f(-13.287712379549449f * (float)(c >> 1) * (1.0f / 512.0f));
            float pe  = (c & 1) ? __cosf(ang) : __sinf(ang);
            v[kk] += pe;
            s  += v[kk];
            ss += v[kk] * v[kk];
        }
        #pragma unroll
        for (int off = 1; off < 64; off <<= 1) {
            s  += __shfl_xor(s, off);
            ss += __shfl_xor(ss, off);
        }
        __shared__ float red_s[4], red_ss[4];
        int wave = tid >> 6, lane = tid & 63;
        if (lane == 0) { red_s[wave] = s; red_ss[wave] = ss; }
        __syncthreads();
        float S  = red_s[0] + red_s[1] + red_s[2] + red_s[3];
        float SS = red_ss[0] + red_ss[1] + red_ss[2] + red_ss[3];
        float mu   = S * (1.0f / 1024.0f);
        float var  = SS * (1.0f / 1024.0f) - mu * mu;
        float rstd = rsqrtf(var + 1e-5f);
        #pragma unroll
        for (int kk = 0; kk < 4; ++kk) {
            int c = tid * 4 + kk;
            float y = (v[kk] - mu) * rstd * gamma[c] + beta[c];
            x[(size_t)row * 1024 + c] = __float2bfloat16(y);
        }
    } else {
        // ---- W transpose + cast ----
        __shared__ __hip_bfloat16 tile[32][33];
        int wid = blockIdx.x - 4096;         // 0..3071
        int zz  = wid >> 10;
        int rem = wid & 1023;
        int bx = rem & 31, by = rem >> 5;
        int tx = tid & 31, ty = tid >> 5;    // (32,8)
        const float* src = (zz == 0) ? Wq : (zz == 1) ? Wk : Wv;
        __hip_bfloat16* dst = Wt + (size_t)zz * 1024 * 1024;
        int x0 = bx * 32, y0 = by * 32;
        #pragma unroll
        for (int kk = 0; kk < 4; ++kk)
            tile[ty + 8 * kk][tx] =
                __float2bfloat16(src[(size_t)(y0 + ty + 8 * kk) * 1024 + x0 + tx]);
        __syncthreads();
        #pragma unroll
        for (int kk = 0; kk < 4; ++kk)
            dst[(size_t)(x0 + ty + 8 * kk) * 1024 + y0 + tx] = tile[tx][ty + 8 * kk];
    }
}

// ---------------------------------------------------------------------------
// Kernel 2: fused QKV GEMM. m97 loop (BK=64, XOR-swizzled LDS), coalesced
// LDS-bounce epilogue. For t==2 (V) the bounce is written TRANSPOSED and
// stored directly to vt[bh][d][token] — vt_kernel is fused away.
// ---------------------------------------------------------------------------
__global__ __launch_bounds__(256) void qkv_gemm(
    const __hip_bfloat16* __restrict__ X,    // [4096,1024] bf16
    const __hip_bfloat16* __restrict__ Wt,   // [3][1024][1024] bf16 N-major
    const float* __restrict__ bq,
    const float* __restrict__ bk,
    const float* __restrict__ bv,
    __hip_bfloat16* __restrict__ qkv,        // [2][4096][1024] bf16 (q,k only)
    __hip_bfloat16* __restrict__ vt)         // [64][64][1024] bf16
{
    union SMem {
        struct { __hip_bfloat16 A[128 * 64]; __hip_bfloat16 B[128 * 64]; } s;
        __hip_bfloat16 C[128 * 132];         // epilogue bounce (pad 132)
    };
    __shared__ __align__(16) SMem sm;

    const int id   = blockIdx.x;             // 0..767
    const int xcd  = id & 7;
    const int rest = id >> 3;                // 0..95
    const int j    = rest % 3;
    const int mblk = rest / 3;               // 0..31
    const int m0   = mblk * 128;
    const int n0   = (xcd * 3 + j) * 128;    // 0..2944
    const int t    = n0 >> 10;
    const int nn0  = n0 & 1023;
    const __hip_bfloat16* W = Wt + (size_t)t * 1024 * 1024;

    const int tid  = threadIdx.x;
    const int wave = tid >> 6, lane = tid & 63;
    const int wm = wave & 1, wn = wave >> 1;
    const int lm = lane & 15, quad = lane >> 4;

    const int srow = lane >> 3;                        // 0..7
    const int skc  = ((lane & 7) ^ srow) * 8;          // element offset
    const int rbase = wave * 32;                       // rows this wave stages
    const __hip_bfloat16* gA = X + (size_t)(m0 + rbase + srow) * 1024 + skc;
    const __hip_bfloat16* gB = W + (size_t)(nn0 + rbase + srow) * 1024 + skc;
    __hip_bfloat16* lA = sm.s.A + rbase * 64;
    __hip_bfloat16* lB = sm.s.B + rbase * 64;

    f32x4 acc[4][4];
    #pragma unroll
    for (int i = 0; i < 4; ++i)
        #pragma unroll
        for (int jj = 0; jj < 4; ++jj)
            acc[i][jj] = (f32x4){0.f, 0.f, 0.f, 0.f};

    for (int k0 = 0; k0 < 1024; k0 += 64) {
        #pragma unroll
        for (int n = 0; n < 4; ++n) {
            gld16(gA + (size_t)n * 8 * 1024 + k0, lA + n * 8 * 64);
            gld16(gB + (size_t)n * 8 * 1024 + k0, lB + n * 8 * 64);
        }
        __syncthreads();

        bf16x8 a[2][4], b[2][4];
        #pragma unroll
        for (int ks = 0; ks < 2; ++ks) {
            #pragma unroll
            for (int i = 0; i < 4; ++i) {
                int row = wm * 64 + i * 16 + lm;
                a[ks][i] = *(const bf16x8*)(sm.s.A + (size_t)row * 64
                                            + (((ks * 4 + quad) ^ (lm & 7)) * 8));
            }
            #pragma unroll
            for (int jj = 0; jj < 4; ++jj) {
                int row = wn * 64 + jj * 16 + lm;
                b[ks][jj] = *(const bf16x8*)(sm.s.B + (size_t)row * 64
                                             + (((ks * 4 + quad) ^ (lm & 7)) * 8));
            }
        }
        __syncthreads();

        #pragma unroll
        for (int ks = 0; ks < 2; ++ks)
            #pragma unroll
            for (int i = 0; i < 4; ++i)
                #pragma unroll
                for (int jj = 0; jj < 4; ++jj)
                    acc[i][jj] = __builtin_amdgcn_mfma_f32_16x16x32_bf16(a[ks][i], b[ks][jj], acc[i][jj], 0, 0, 0);
    }

    const float* bias = (t == 0) ? bq : (t == 1) ? bk : bv;
    if (t < 2) {
        // ---- row-major bounce -> coalesced 16B stores into qkv[t] ----
        #pragma unroll
        for (int jj = 0; jj < 4; ++jj) {
            int col = wn * 64 + jj * 16 + lm;
            float bb = bias[nn0 + col];
            #pragma unroll
            for (int i = 0; i < 4; ++i)
                #pragma unroll
                for (int r = 0; r < 4; ++r) {
                    int row = wm * 64 + i * 16 + quad * 4 + r;
                    sm.C[(size_t)row * 132 + col] = __float2bfloat16(acc[i][jj][r] + bb);
                }
        }
        __syncthreads();
        __hip_bfloat16* out = qkv + (size_t)t * 4096 * 1024;
        #pragma unroll
        for (int c = 0; c < 8; ++c) {
            int g = tid + 256 * c;               // 0..2047 chunks of 16B
            int row = g >> 4;
            int colc = (g & 15) * 8;
            bf16x8 vch = *(const bf16x8*)&sm.C[(size_t)row * 132 + colc];
            *(bf16x8*)(out + (size_t)(m0 + row) * 1024 + nn0 + colc) = vch;
        }
    } else {
        // ---- transposed bounce C[col][row] -> vt[bh][d][token] ----
        #pragma unroll
        for (int jj = 0; jj < 4; ++jj) {
            int col = wn * 64 + jj * 16 + lm;
            float bb = bias[nn0 + col];
            #pragma unroll
            for (int i = 0; i < 4; ++i)
                #pragma unroll
                for (int r = 0; r < 4; ++r) {
                    int row = wm * 64 + i * 16 + quad * 4 + r;
                    sm.C[(size_t)col * 132 + row] = __float2bfloat16(acc[i][jj][r] + bb);
                }
        }
        __syncthreads();
        const int bbase = (m0 >> 10) * 16 + (nn0 >> 6);
        const int mloc  = m0 & 1023;
        #pragma unroll
        for (int c = 0; c < 8; ++c) {
            int g = tid + 256 * c;               // 0..2047
            int col = g >> 4;                    // 0..127
            int rch = (g & 15) * 8;              // token chunk
            bf16x8 vch = *(const bf16x8*)&sm.C[(size_t)col * 132 + rch];
            int bh = bbase + (col >> 6);
            int d  = col & 63;
            *(bf16x8*)(vt + ((size_t)bh * 64 + d) * 1024 + mloc + rch) = vch;
        }
    }
}

// ---------------------------------------------------------------------------
// Kernel 3: flash attention v8 — LDS-staged K/V, 128-key tiles, 2 compute
// sub-rounds per stage (barriers halved vs v7). 128 q/block, 32 q/wave,
// max-free softmax, P^T via wave-private LDS (ds ops in-order per wave).
// ---------------------------------------------------------------------------
__global__ __launch_bounds__(256, 2) void attn_kernel(
    const __hip_bfloat16* __restrict__ q,    // [4096,1024]
    const __hip_bfloat16* __restrict__ k,    // [4096,1024]
    const __hip_bfloat16* __restrict__ vt,   // [64][64][1024]
    float* __restrict__ out)                 // [4096,1024] f32
{
    __shared__ __align__(16) __hip_bfloat16 Kbuf[128 * 64];   // 16 KB [key][d]
    __shared__ __align__(16) __hip_bfloat16 Vbuf[2][64 * 64]; // 16 KB [half][d][key]
    __shared__ short ldsPT[4][32][72];                        // 18 KB
    const int id   = blockIdx.x;             // 0..511
    const int bh   = (id & 7) * 8 + ((id >> 3) & 7);  // XCD-local K/V
    const int qblk = id >> 6;                // 0..7
    const int b = bh >> 4, h = bh & 15;
    const int wave = threadIdx.x >> 6, lane = threadIdx.x & 63;
    const int lm = lane & 15, quad = lane >> 4;
    const int qbase = qblk * 128 + wave * 32;
    const float CEXP = 0.18033688011112042f; // (1/8) * log2(e)

    // Q as B-operand frags (col n = q = lm, k = d) — loaded once
    bf16x8 bqf[2][2];
    #pragma unroll
    for (int i = 0; i < 2; ++i)
        #pragma unroll
        for (int ks = 0; ks < 2; ++ks)
            bqf[i][ks] = *(const bf16x8*)(q + (size_t)(b * 1024 + qbase + 16 * i + lm) * 1024
                                            + h * 64 + ks * 32 + quad * 8);

    const __hip_bfloat16* kg = k + (size_t)(b * 1024) * 1024 + h * 64;   // [key][d]
    const __hip_bfloat16* vg = vt + (size_t)bh * 64 * 1024;              // [d][key]
    const int srow = lane >> 3;                  // 0..7
    const int skc  = ((lane & 7) ^ srow) * 8;    // swizzled source chunk

    f32x4 OT[4][2];        // [nt = d-tile][i = q-tile]; rows = d, cols = q
    float li[2] = {0.f, 0.f};
    #pragma unroll
    for (int nt = 0; nt < 4; ++nt)
        #pragma unroll
        for (int i = 0; i < 2; ++i)
            OT[nt][i] = (f32x4){0.f, 0.f, 0.f, 0.f};

    for (int kt = 0; kt < 1024; kt += 128) {
        // ---- stage K [128 keys][64 d] and V [2][64 d][64 keys] ----
        // K: wave stages rows wave*32 + n*8 (+srow)
        #pragma unroll
        for (int n = 0; n < 4; ++n) {
            int r0 = wave * 32 + n * 8;
            gld16(kg + (size_t)(kt + r0 + srow) * 1024 + skc, Kbuf + r0 * 64);
        }
        // V: half = wave>>1, d rows (wave&1)*32 + n*8 (+srow)
        {
            int half = wave >> 1;
            #pragma unroll
            for (int n = 0; n < 4; ++n) {
                int d0 = (wave & 1) * 32 + n * 8;
                gld16(vg + (size_t)(d0 + srow) * 1024 + kt + half * 64 + skc,
                      Vbuf[half] + d0 * 64);
            }
        }
        __syncthreads();

        #pragma unroll
        for (int sr = 0; sr < 2; ++sr) {
            // fragment reads for this sub-round (must precede barrier #2)
            bf16x8 ak[4][2], av[4][2];
            #pragma unroll
            for (int jt = 0; jt < 4; ++jt)
                #pragma unroll
                for (int ks = 0; ks < 2; ++ks)
                    ak[jt][ks] = *(const bf16x8*)(Kbuf + (size_t)(sr * 64 + 16 * jt + lm) * 64
                                                  + (((ks * 4 + quad) ^ (lm & 7)) * 8));
            #pragma unroll
            for (int nt = 0; nt < 4; ++nt)
                #pragma unroll
                for (int ks = 0; ks < 2; ++ks)
                    av[nt][ks] = *(const bf16x8*)(Vbuf[sr] + (size_t)(16 * nt + lm) * 64
                                                  + (((ks * 4 + quad) ^ (lm & 7)) * 8));
            if (sr == 1) __syncthreads();   // all tile reads done; next stage may write

            // ---- S^T = K·Q^T ----
            f32x4 ST[2][4];
            #pragma unroll
            for (int i = 0; i < 2; ++i)
                #pragma unroll
                for (int jt = 0; jt < 4; ++jt)
                    ST[i][jt] = (f32x4){0.f, 0.f, 0.f, 0.f};
            #pragma unroll
            for (int ks = 0; ks < 2; ++ks)
                #pragma unroll
                for (int i = 0; i < 2; ++i)
                    #pragma unroll
                    for (int jt = 0; jt < 4; ++jt)
                        ST[i][jt] = __builtin_amdgcn_mfma_f32_16x16x32_bf16(ak[jt][ks], bqf[i][ks], ST[i][jt], 0, 0, 0);

            // ---- P = exp2(S*CEXP), wave-private LDS (b64 writes) ----
            #pragma unroll
            for (int i = 0; i < 2; ++i)
                #pragma unroll
                for (int jt = 0; jt < 4; ++jt) {
                    bf16x4 pk;
                    #pragma unroll
                    for (int r = 0; r < 4; ++r) {
                        float p = __builtin_amdgcn_exp2f(ST[i][jt][r] * CEXP);
                        li[i] += p;
                        pk[r] = f2bf_s(p);
                    }
                    *(bf16x4*)&ldsPT[wave][16 * i + lm][16 * jt + quad * 4] = pk;
                }

            // ---- O^T += V^T·P^T (in-wave DS ordering; compiler RAW waits) ----
            bf16x8 bp[2][2];
            #pragma unroll
            for (int i = 0; i < 2; ++i)
                #pragma unroll
                for (int ks = 0; ks < 2; ++ks)
                    bp[i][ks] = *(const bf16x8*)&ldsPT[wave][16 * i + lm][ks * 32 + quad * 8];
            #pragma unroll
            for (int ks = 0; ks < 2; ++ks)
                #pragma unroll
                for (int nt = 0; nt < 4; ++nt)
                    #pragma unroll
                    for (int i = 0; i < 2; ++i)
                        OT[nt][i] = __builtin_amdgcn_mfma_f32_16x16x32_bf16(av[nt][ks], bp[i][ks], OT[nt][i], 0, 0, 0);
        }
    }

    // li per-lane partial (q = lm): reduce across the 4 quads
    #pragma unroll
    for (int i = 0; i < 2; ++i) {
        li[i] += __shfl_xor(li[i], 16);
        li[i] += __shfl_xor(li[i], 32);
    }

    #pragma unroll
    for (int i = 0; i < 2; ++i) {
        float inv = 1.0f / li[i];
        int qrow = qbase + 16 * i + lm;
        #pragma unroll
        for (int nt = 0; nt < 4; ++nt) {
            float4 o4 = {OT[nt][i][0] * inv, OT[nt][i][1] * inv,
                         OT[nt][i][2] * inv, OT[nt][i][3] * inv};
            *(float4*)(out + (size_t)(b * 1024 + qrow) * 1024 + h * 64 + 16 * nt + quad * 4) = o4;
        }
    }
}

// ---------------------------------------------------------------------------
extern "C" void kernel_launch(void* const* d_in, const int* in_sizes, int n_in,
                              void* d_out, int out_size, void* d_ws, size_t ws_size,
                              hipStream_t stream)
{
    const float* emb   = (const float*)d_in[0];
    const float* gamma = (const float*)d_in[1];
    const float* beta  = (const float*)d_in[2];
    const float* Wq    = (const float*)d_in[3];
    const float* bq    = (const float*)d_in[4];
    const float* Wk    = (const float*)d_in[5];
    const float* bk    = (const float*)d_in[6];
    const float* Wv    = (const float*)d_in[7];
    const float* bv    = (const float*)d_in[8];
    float* out = (float*)d_out;

    __hip_bfloat16* ws  = (__hip_bfloat16*)d_ws;
    __hip_bfloat16* x   = ws;                            //  4M elems bf16
    __hip_bfloat16* Wt  = x   + (size_t)4096 * 1024;     //  3M elems
    __hip_bfloat16* qkv = Wt  + (size_t)3 * 1024 * 1024; //  8M elems (q,k)
    __hip_bfloat16* vt  = qkv + (size_t)2 * 4096 * 1024; //  4M elems (38MB)

    peln_wt_kernel<<<4096 + 3072, 256, 0, stream>>>(emb, gamma, beta, Wq, Wk, Wv, x, Wt);
    qkv_gemm<<<768, 256, 0, stream>>>(x, Wt, bq, bk, bv, qkv, vt);
    attn_kernel<<<512, 256, 0, stream>>>(qkv, qkv + (size_t)4096 * 1024, vt, out);
}